// Round 1
// baseline (2881.011 us; speedup 1.0000x reference)
//
#include <hip/hip_runtime.h>
#include <math.h>

#define NN 50000
#define TT 12
#define EE 800000
#define DIM 128

typedef short bf16x8 __attribute__((ext_vector_type(8)));
typedef float f32x4 __attribute__((ext_vector_type(4)));

__device__ __forceinline__ float sigmoidf_(float x) { return 1.0f / (1.0f + expf(-x)); }
__device__ __forceinline__ float geluf_(float x) {
  return 0.5f * x * (1.0f + erff(x * 0.70710678118654752440f));
}
__device__ __forceinline__ unsigned short f2b(float f) {
  union { float f; unsigned u; } v;
  v.f = f;
  unsigned r = (v.u + 0x7fffu + ((v.u >> 16) & 1u)) >> 16;
  return (unsigned short)r;
}
__device__ __forceinline__ float blo(unsigned u) {
  union { unsigned x; float f; } v; v.x = u << 16; return v.f;
}
__device__ __forceinline__ float bhi(unsigned u) {
  union { unsigned x; float f; } v; v.x = u & 0xffff0000u; return v.f;
}
__device__ __forceinline__ float b2f(unsigned short b) {
  union { unsigned u; float f; } v; v.u = ((unsigned)b) << 16; return v.f;
}
__device__ __forceinline__ unsigned short f2h(float f) {
  union { _Float16 h; unsigned short s; } v; v.h = (_Float16)f; return v.s;
}
__device__ __forceinline__ float h2f(unsigned u) {
  union { unsigned short s; _Float16 h; } v; v.s = (unsigned short)u; return (float)v.h;
}

// ---------------- graph preprocessing ----------------

__global__ void deg_kernel(const int* __restrict__ src, const int* __restrict__ dst,
                           int* __restrict__ ds, int* __restrict__ dd) {
  int e = blockIdx.x * 256 + threadIdx.x;
  if (e < EE) {
    atomicAdd(&ds[src[e]], 1);
    atomicAdd(&dd[dst[e]], 1);
  }
}

__global__ void norm_kernel(const int* __restrict__ ds, const int* __restrict__ dd,
                            float* __restrict__ ns, float* __restrict__ nd) {
  int i = blockIdx.x * 256 + threadIdx.x;
  if (i < NN) {
    ns[i] = rsqrtf((float)(ds[i] > 1 ? ds[i] : 1));
    nd[i] = rsqrtf((float)(dd[i] > 1 ? dd[i] : 1));
  }
}

__global__ void scan_kernel(const int* __restrict__ cnt, int* __restrict__ row_ptr, int n) {
  __shared__ int sm[1024];
  __shared__ int carry;
  int tid = threadIdx.x;
  if (tid == 0) carry = 0;
  __syncthreads();
  for (int base = 0; base < n; base += 1024) {
    int v = (base + tid < n) ? cnt[base + tid] : 0;
    sm[tid] = v;
    __syncthreads();
    for (int off = 1; off < 1024; off <<= 1) {
      int t = (tid >= off) ? sm[tid - off] : 0;
      __syncthreads();
      sm[tid] += t;
      __syncthreads();
    }
    int incl = sm[tid];
    if (base + tid < n) row_ptr[base + tid] = carry + incl - v;
    int tot = sm[1023];
    __syncthreads();
    if (tid == 0) carry += tot;
    __syncthreads();
  }
  if (tid == 0) row_ptr[n] = carry;
}

__global__ void csr_kernel(const int* __restrict__ src, const int* __restrict__ dst,
                           const int* __restrict__ row_ptr, int* __restrict__ fill,
                           int* __restrict__ col) {
  int e = blockIdx.x * 256 + threadIdx.x;
  if (e < EE) {
    int d = dst[e];
    int pos = row_ptr[d] + atomicAdd(&fill[d], 1);
    col[pos] = src[e];
  }
}

// ---------------- weight prep ----------------
// W2bt: [128][128] n-major = Wg2^T (bf16)
// Wcomb: [640][128] n-major: rows 0..127 = Wg1^T, rows 128..639 = w_ih (bf16)
// whhb:  [512][128] n-major = w_hh (bf16)
// bgate: b_ih + b_hh

__global__ void prep_w(const float* __restrict__ Wg1, const float* __restrict__ Wg2,
                       const float* __restrict__ wih, const float* __restrict__ whh,
                       const float* __restrict__ bih, const float* __restrict__ bhh,
                       unsigned short* __restrict__ W2bt, unsigned short* __restrict__ Wcomb,
                       unsigned short* __restrict__ whhb, float* __restrict__ bgate) {
  int i = blockIdx.x * 256 + threadIdx.x;
  if (i < 16384) {
    int n = i >> 7, k = i & 127;
    W2bt[i] = f2b(Wg2[k * 128 + n]);
  }
  int j = i - 16384;
  if (j >= 0 && j < 81920) {
    int n = j >> 7, k = j & 127;
    Wcomb[j] = f2b(n < 128 ? Wg1[k * 128 + n] : wih[(n - 128) * 128 + k]);
  }
  int q = i - (16384 + 81920);
  if (q >= 0 && q < 65536) whhb[q] = f2b(whh[q]);
  if (i < 512) bgate[i] = bih[i] + bhh[i];
}

// ---------------- batched MFMA GEMMs (M = 600000, K = 128) ----------------
#define LDT 40

// Fused: cb = blockIdx.x selects the 128-col weight block of Wcomb.
//   cb == 0 : z1[row] = ns[row/TT] * ( bf16(h[row]) @ Wg1 )      -> C (bf16)
//   cb >= 1 : xg[row][c][gate=cb-1] = f16( bf16(h[row]) @ w_ih^T ) (gate-interleaved)
__global__ __launch_bounds__(256) void gemm_h_fused(
    const float* __restrict__ A, const float* __restrict__ ns,
    const unsigned short* __restrict__ Wcomb, unsigned short* __restrict__ C,
    unsigned short* __restrict__ xg, int M) {
  __shared__ unsigned short As[128 * LDT];
  __shared__ unsigned short Bs[128 * LDT];
  const int cb = blockIdx.x;
  const unsigned short* Bt = Wcomb + cb * 16384;
  const int tid = threadIdx.x;
  const int lane = tid & 63, wid = tid >> 6;
  const int quad = lane >> 4, l16 = lane & 15;
  const int row0 = blockIdx.y * 128;
  const int wm = (wid >> 1) * 64, wn = (wid & 1) * 64;
  f32x4 acc[4][4] = {};
  for (int k0 = 0; k0 < 128; k0 += 32) {
#pragma unroll
    for (int rds = 0; rds < 2; rds++) {
      int idx = (rds * 256 + tid) * 8;
      int m = idx >> 5, c = idx & 31;
      int gr = row0 + m;
      if (gr >= M) gr = M - 1;
      const float4 va = *(const float4*)(A + (size_t)gr * 128 + k0 + c);
      const float4 vb = *(const float4*)(A + (size_t)gr * 128 + k0 + c + 4);
      unsigned short* d = &As[m * LDT + c];
      d[0] = f2b(va.x); d[1] = f2b(va.y); d[2] = f2b(va.z); d[3] = f2b(va.w);
      d[4] = f2b(vb.x); d[5] = f2b(vb.y); d[6] = f2b(vb.z); d[7] = f2b(vb.w);
      *(uint4*)(&Bs[m * LDT + c]) = *(const uint4*)(Bt + m * 128 + k0 + c);
    }
    __syncthreads();
    bf16x8 af[4], bfr[4];
#pragma unroll
    for (int im = 0; im < 4; im++)
      af[im] = *(const bf16x8*)(&As[(wm + im * 16 + l16) * LDT + quad * 8]);
#pragma unroll
    for (int in = 0; in < 4; in++)
      bfr[in] = *(const bf16x8*)(&Bs[(wn + in * 16 + l16) * LDT + quad * 8]);
#pragma unroll
    for (int im = 0; im < 4; im++)
#pragma unroll
      for (int in = 0; in < 4; in++)
        acc[im][in] = __builtin_amdgcn_mfma_f32_16x16x32_bf16(af[im], bfr[in], acc[im][in], 0, 0, 0);
    __syncthreads();
  }
  if (cb == 0) {
#pragma unroll
    for (int im = 0; im < 4; im++)
#pragma unroll
      for (int r = 0; r < 4; r++) {
        int row = row0 + wm + im * 16 + quad * 4 + r;
        if (row < M) {
          float s = ns[row / TT];
#pragma unroll
          for (int in = 0; in < 4; in++)
            C[(size_t)row * 128 + wn + in * 16 + l16] = f2b(acc[im][in][r] * s);
        }
      }
  } else {
    const int g = cb - 1;
#pragma unroll
    for (int im = 0; im < 4; im++)
#pragma unroll
      for (int r = 0; r < 4; r++) {
        int row = row0 + wm + im * 16 + quad * 4 + r;
        if (row < M)
#pragma unroll
          for (int in = 0; in < 4; in++) {
            int colc = wn + in * 16 + l16;
            xg[(size_t)row * 512 + colc * 4 + g] = f2h(acc[im][in][r]);
          }
      }
  }
}

// z2 = y1s @ W2bt^T  (bf16 A)
__global__ __launch_bounds__(256) void gemm_bf16A(
    const unsigned short* __restrict__ A, const unsigned short* __restrict__ Bt,
    unsigned short* __restrict__ C, int M) {
  __shared__ unsigned short As[128 * LDT];
  __shared__ unsigned short Bs[128 * LDT];
  const int tid = threadIdx.x;
  const int lane = tid & 63, wid = tid >> 6;
  const int quad = lane >> 4, l16 = lane & 15;
  const int row0 = blockIdx.x * 128;
  const int wm = (wid >> 1) * 64, wn = (wid & 1) * 64;
  f32x4 acc[4][4] = {};
  for (int k0 = 0; k0 < 128; k0 += 32) {
#pragma unroll
    for (int rds = 0; rds < 2; rds++) {
      int idx = (rds * 256 + tid) * 8;
      int m = idx >> 5, c = idx & 31;
      int gr = row0 + m;
      if (gr >= M) gr = M - 1;
      *(uint4*)(&As[m * LDT + c]) = *(const uint4*)(A + (size_t)gr * 128 + k0 + c);
      *(uint4*)(&Bs[m * LDT + c]) = *(const uint4*)(Bt + m * 128 + k0 + c);
    }
    __syncthreads();
    bf16x8 af[4], bfr[4];
#pragma unroll
    for (int im = 0; im < 4; im++)
      af[im] = *(const bf16x8*)(&As[(wm + im * 16 + l16) * LDT + quad * 8]);
#pragma unroll
    for (int in = 0; in < 4; in++)
      bfr[in] = *(const bf16x8*)(&Bs[(wn + in * 16 + l16) * LDT + quad * 8]);
#pragma unroll
    for (int im = 0; im < 4; im++)
#pragma unroll
      for (int in = 0; in < 4; in++)
        acc[im][in] = __builtin_amdgcn_mfma_f32_16x16x32_bf16(af[im], bfr[in], acc[im][in], 0, 0, 0);
    __syncthreads();
  }
#pragma unroll
  for (int im = 0; im < 4; im++)
#pragma unroll
    for (int r = 0; r < 4; r++) {
      int row = row0 + wm + im * 16 + quad * 4 + r;
      if (row < M)
#pragma unroll
        for (int in = 0; in < 4; in++)
          C[(size_t)row * 128 + wn + in * 16 + l16] = f2b(acc[im][in][r]);
    }
}

// ---------------- batched SpMM ----------------

template <bool SCALE_OUT>
__global__ __launch_bounds__(256) void spmm_b(
    const unsigned short* __restrict__ z, const int* __restrict__ rowp,
    const int* __restrict__ colx, const float* __restrict__ ns,
    const float* __restrict__ nd, const float* __restrict__ bg,
    unsigned short* __restrict__ y) {
  int d = (blockIdx.x * 256 + threadIdx.x) >> 6;
  int lane = threadIdx.x & 63;
  if (d >= NN) return;
  int beg = rowp[d], end = rowp[d + 1];
  float acc[3][8] = {};
  int j = beg;
  int s = (j < end) ? colx[j] : 0;
  while (j < end) {
    int snext = (j + 1 < end) ? colx[j + 1] : 0;
    const unsigned short* base = z + (size_t)s * 1536 + lane * 8;
#pragma unroll
    for (int r = 0; r < 3; r++) {
      uint4 v = *(const uint4*)(base + r * 512);
      acc[r][0] += blo(v.x); acc[r][1] += bhi(v.x);
      acc[r][2] += blo(v.y); acc[r][3] += bhi(v.y);
      acc[r][4] += blo(v.z); acc[r][5] += bhi(v.z);
      acc[r][6] += blo(v.w); acc[r][7] += bhi(v.w);
    }
    s = snext;
    j++;
  }
  float scn = nd[d];
  float sco = SCALE_OUT ? ns[d] : 1.0f;
  float bgv[8];
#pragma unroll
  for (int k = 0; k < 8; k++) bgv[k] = bg[(lane * 8 + k) & 127];
  unsigned short* outp = y + (size_t)d * 1536 + lane * 8;
#pragma unroll
  for (int r = 0; r < 3; r++) {
    unsigned short o[8];
#pragma unroll
    for (int k = 0; k < 8; k++)
      o[k] = f2b(sco * geluf_(acc[r][k] * scn + bgv[k]));
    *(uint4*)(outp + r * 512) = *(const uint4*)o;
  }
}

// ---------------- batched column mean ----------------

__global__ void colmean_b(const unsigned short* __restrict__ x, float* __restrict__ out) {
  int t = blockIdx.x;
  int cc = threadIdx.x & 127;
  int half = threadIdx.x >> 7;
  float s = 0.f;
  for (int n = blockIdx.y * 2 + half; n < NN; n += 64)
    s += b2f(x[((size_t)n * TT + t) * 128 + cc]);
  __shared__ float sm[256];
  sm[threadIdx.x] = s;
  __syncthreads();
  if (threadIdx.x < 128)
    atomicAdd(&out[t * 128 + cc], (sm[threadIdx.x] + sm[threadIdx.x + 128]) * (1.0f / NN));
}

// ---------------- LSTM: h-recurrence only, w_hh resident in LDS ----------------
// block = 512 thr (8 waves), 64 rows. gates = xg (precomputed x@w_ih^T, f16,
// gate-interleaved) + Hp @ w_hh^T (MFMA from LDS-resident weights).
// Per t: 4 pure ds_read+MFMA k-steps, 2 barriers. t=0 skips MFMA (h_prev=0).
#define HPLD 136
#define WLD 136

__global__ __launch_bounds__(512, 2) void lstm_hh(
    const unsigned short* __restrict__ whhb, const unsigned short* __restrict__ xg,
    const float* __restrict__ bgate, float* __restrict__ ht_out, int M) {
  __shared__ unsigned short Ws[512 * WLD];  // 136 KB
  __shared__ unsigned short Hp[64 * HPLD];  // 17 KB
  const int tid = threadIdx.x;
  const int lane = tid & 63;
  const int w = tid >> 6;
  const int quad = lane >> 4, l16 = lane & 15;
  const int row0 = blockIdx.x * 64;
  const int colg = w * 16 + l16;

  // one-time weight staging: 512x128 bf16, 16B per thread-iter, coalesced
#pragma unroll
  for (int it = 0; it < 16; it++) {
    int idx = it * 512 + tid;
    int n = idx >> 4, c = (idx & 15) * 8;
    *(uint4*)(&Ws[n * WLD + c]) = *(const uint4*)(whhb + n * 128 + c);
  }

  float cs[4][4], hacc[4][4];
#pragma unroll
  for (int im = 0; im < 4; im++)
#pragma unroll
    for (int r = 0; r < 4; r++) { cs[im][r] = 0.f; hacc[im][r] = 0.f; }

  const float bi = bgate[colg], bff = bgate[128 + colg];
  const float bgg = bgate[256 + colg], bo = bgate[384 + colg];
  __syncthreads();

  for (int t = 0; t < TT; t++) {
    // prefetch this step's x-gates (4 gates packed per 8B) — hides under MFMA
    uint2 xv[4][4];
#pragma unroll
    for (int im = 0; im < 4; im++)
#pragma unroll
      for (int r = 0; r < 4; r++) {
        int gr = row0 + im * 16 + quad * 4 + r;
        int grc = gr < M ? gr : M - 1;
        xv[im][r] = *(const uint2*)(xg + ((size_t)grc * TT + t) * 512 + colg * 4);
      }

    f32x4 acc[4][4] = {};  // [im][gate]
    if (t) {
#pragma unroll
      for (int k0 = 0; k0 < 128; k0 += 32) {
        bf16x8 af[4];
#pragma unroll
        for (int im = 0; im < 4; im++)
          af[im] = *(const bf16x8*)(&Hp[(im * 16 + l16) * HPLD + k0 + quad * 8]);
#pragma unroll
        for (int g = 0; g < 4; g++) {
          bf16x8 bf = *(const bf16x8*)(&Ws[(g * 128 + colg) * WLD + k0 + quad * 8]);
#pragma unroll
          for (int im = 0; im < 4; im++)
            acc[im][g] = __builtin_amdgcn_mfma_f32_16x16x32_bf16(af[im], bf, acc[im][g], 0, 0, 0);
        }
      }
      __syncthreads();  // all waves done reading Hp for this t
    }

    // fused pointwise; h stays in LDS, c stays in registers
#pragma unroll
    for (int im = 0; im < 4; im++)
#pragma unroll
      for (int r = 0; r < 4; r++) {
        float iv = sigmoidf_(acc[im][0][r] + h2f(xv[im][r].x & 0xffffu) + bi);
        float fv = sigmoidf_(acc[im][1][r] + h2f(xv[im][r].x >> 16) + bff);
        float gv = tanhf(acc[im][2][r] + h2f(xv[im][r].y & 0xffffu) + bgg);
        float ov = sigmoidf_(acc[im][3][r] + h2f(xv[im][r].y >> 16) + bo);
        float cn = fv * cs[im][r] + iv * gv;
        cs[im][r] = cn;
        float ho = ov * tanhf(cn);
        hacc[im][r] += ho;
        Hp[(im * 16 + quad * 4 + r) * HPLD + colg] = f2b(ho);
      }
    __syncthreads();
  }
#pragma unroll
  for (int im = 0; im < 4; im++)
#pragma unroll
    for (int r = 0; r < 4; r++) {
      int gr = row0 + im * 16 + quad * 4 + r;
      if (gr < M) ht_out[(size_t)gr * 128 + colg] = hacc[im][r] * (1.0f / TT);
    }
}

// ---------------- host ----------------

extern "C" void kernel_launch(void* const* d_in, const int* in_sizes, int n_in,
                              void* d_out, int out_size, void* d_ws, size_t ws_size,
                              hipStream_t stream) {
  const float* h   = (const float*)d_in[0];
  const int*   src = (const int*)d_in[1];
  const int*   dst = (const int*)d_in[2];
  const float* Wg1 = (const float*)d_in[3];
  const float* bg1 = (const float*)d_in[4];
  const float* Wg2 = (const float*)d_in[5];
  const float* bg2 = (const float*)d_in[6];
  const float* wih = (const float*)d_in[7];
  const float* whh = (const float*)d_in[8];
  const float* bih = (const float*)d_in[9];
  const float* bhh = (const float*)d_in[10];

  float* out = (float*)d_out;
  float* hs_out = out;            // 12*128
  float* ht_out = out + TT * DIM; // N*128

  char* p = (char*)d_ws;
  auto alloc = [&](size_t bytes) -> void* {
    void* r = (void*)p;
    p += (bytes + 255) & ~(size_t)255;
    return r;
  };
  const size_t MB = (size_t)NN * TT * DIM;  // 76.8M elements
  unsigned short* bufA = (unsigned short*)alloc(MB * 2);            // z1 -> z2
  unsigned short* bufB = (unsigned short*)alloc(MB * 2);            // y1s -> y2
  unsigned short* xgb  = (unsigned short*)alloc((size_t)NN * TT * 512 * 2);  // x-gates f16
  unsigned short* W2bt = (unsigned short*)alloc(16384 * 2);
  unsigned short* Wcomb= (unsigned short*)alloc(81920 * 2);
  unsigned short* whhb = (unsigned short*)alloc(65536 * 2);
  float* bgate = (float*)alloc(512 * 4);
  float* ns    = (float*)alloc(NN * 4);
  float* nd    = (float*)alloc(NN * 4);
  int* degs    = (int*)alloc(NN * 4);
  int* degd    = (int*)alloc(NN * 4);
  int* rowp    = (int*)alloc((NN + 1) * 4);
  int* colx    = (int*)alloc(EE * 4);

  hipMemsetAsync(degs, 0, NN * 4, stream);
  hipMemsetAsync(degd, 0, NN * 4, stream);
  hipMemsetAsync(hs_out, 0, TT * DIM * 4, stream);

  deg_kernel<<<(EE + 255) / 256, 256, 0, stream>>>(src, dst, degs, degd);
  norm_kernel<<<(NN + 255) / 256, 256, 0, stream>>>(degs, degd, ns, nd);
  scan_kernel<<<1, 1024, 0, stream>>>(degd, rowp, NN);
  hipMemsetAsync(degs, 0, NN * 4, stream);  // reuse as fill counters
  csr_kernel<<<(EE + 255) / 256, 256, 0, stream>>>(src, dst, rowp, degs, colx);
  prep_w<<<(16384 + 81920 + 65536 + 255) / 256, 256, 0, stream>>>(
      Wg1, Wg2, wih, whh, bih, bhh, W2bt, Wcomb, whhb, bgate);

  const int M = NN * TT;                  // 600000 batched rows
  const int gblocks = (M + 127) / 128;    // 4688
  const int sblocks = (NN + 3) / 4;       // wave per dst row

  // GCN gemm1 fused with x-gate precompute (cb=0: z1; cb=1..4: gates)
  gemm_h_fused<<<dim3(5, gblocks), 256, 0, stream>>>(h, ns, Wcomb, bufA, xgb, M);
  spmm_b<true><<<sblocks, 256, 0, stream>>>(bufA, rowp, colx, ns, nd, bg1, bufB);
  gemm_bf16A<<<gblocks, 256, 0, stream>>>(bufB, W2bt, bufA, M);
  spmm_b<false><<<sblocks, 256, 0, stream>>>(bufA, rowp, colx, ns, nd, bg2, bufB);
  colmean_b<<<dim3(TT, 32), 256, 0, stream>>>(bufB, hs_out);

  // LSTM: h-recurrence only, weights LDS-resident
  lstm_hh<<<(NN + 63) / 64, 512, 0, stream>>>(whhb, xgb, bgate, ht_out, NN);
}

// Round 2
// 2442.432 us; speedup vs baseline: 1.1796x; 1.1796x over previous
//
#include <hip/hip_runtime.h>
#include <math.h>

#define NN 50000
#define TT 12
#define EE 800000
#define DIM 128

typedef short bf16x8 __attribute__((ext_vector_type(8)));
typedef float f32x4 __attribute__((ext_vector_type(4)));

__device__ __forceinline__ float sigmoidf_(float x) { return 1.0f / (1.0f + expf(-x)); }
__device__ __forceinline__ float geluf_(float x) {
  return 0.5f * x * (1.0f + erff(x * 0.70710678118654752440f));
}
__device__ __forceinline__ unsigned short f2b(float f) {
  union { float f; unsigned u; } v;
  v.f = f;
  unsigned r = (v.u + 0x7fffu + ((v.u >> 16) & 1u)) >> 16;
  return (unsigned short)r;
}
__device__ __forceinline__ float blo(unsigned u) {
  union { unsigned x; float f; } v; v.x = u << 16; return v.f;
}
__device__ __forceinline__ float bhi(unsigned u) {
  union { unsigned x; float f; } v; v.x = u & 0xffff0000u; return v.f;
}
__device__ __forceinline__ float b2f(unsigned short b) {
  union { unsigned u; float f; } v; v.u = ((unsigned)b) << 16; return v.f;
}
__device__ __forceinline__ unsigned short f2h(float f) {
  union { _Float16 h; unsigned short s; } v; v.h = (_Float16)f; return v.s;
}
__device__ __forceinline__ float h2f(unsigned short u) {
  union { unsigned short s; _Float16 h; } v; v.s = u; return (float)v.h;
}

// ---------------- graph preprocessing ----------------

__global__ void deg_kernel(const int* __restrict__ src, const int* __restrict__ dst,
                           int* __restrict__ ds, int* __restrict__ dd) {
  int e = blockIdx.x * 256 + threadIdx.x;
  if (e < EE) {
    atomicAdd(&ds[src[e]], 1);
    atomicAdd(&dd[dst[e]], 1);
  }
}

__global__ void norm_kernel(const int* __restrict__ ds, const int* __restrict__ dd,
                            float* __restrict__ ns, float* __restrict__ nd) {
  int i = blockIdx.x * 256 + threadIdx.x;
  if (i < NN) {
    ns[i] = rsqrtf((float)(ds[i] > 1 ? ds[i] : 1));
    nd[i] = rsqrtf((float)(dd[i] > 1 ? dd[i] : 1));
  }
}

__global__ void scan_kernel(const int* __restrict__ cnt, int* __restrict__ row_ptr, int n) {
  __shared__ int sm[1024];
  __shared__ int carry;
  int tid = threadIdx.x;
  if (tid == 0) carry = 0;
  __syncthreads();
  for (int base = 0; base < n; base += 1024) {
    int v = (base + tid < n) ? cnt[base + tid] : 0;
    sm[tid] = v;
    __syncthreads();
    for (int off = 1; off < 1024; off <<= 1) {
      int t = (tid >= off) ? sm[tid - off] : 0;
      __syncthreads();
      sm[tid] += t;
      __syncthreads();
    }
    int incl = sm[tid];
    if (base + tid < n) row_ptr[base + tid] = carry + incl - v;
    int tot = sm[1023];
    __syncthreads();
    if (tid == 0) carry += tot;
    __syncthreads();
  }
  if (tid == 0) row_ptr[n] = carry;
}

__global__ void csr_kernel(const int* __restrict__ src, const int* __restrict__ dst,
                           const int* __restrict__ row_ptr, int* __restrict__ fill,
                           int* __restrict__ col) {
  int e = blockIdx.x * 256 + threadIdx.x;
  if (e < EE) {
    int d = dst[e];
    int pos = row_ptr[d] + atomicAdd(&fill[d], 1);
    col[pos] = src[e];
  }
}

// ---------------- weight prep ----------------
// W2bt: [128][128] n-major = Wg2^T (bf16)
// Wcomb: [640][128] n-major: rows 0..127 = Wg1^T, rows 128..639 = w_ih (bf16)
// whhb:  [512][128] n-major = w_hh (bf16)
// bgate: b_ih + b_hh

__global__ void prep_w(const float* __restrict__ Wg1, const float* __restrict__ Wg2,
                       const float* __restrict__ wih, const float* __restrict__ whh,
                       const float* __restrict__ bih, const float* __restrict__ bhh,
                       unsigned short* __restrict__ W2bt, unsigned short* __restrict__ Wcomb,
                       unsigned short* __restrict__ whhb, float* __restrict__ bgate) {
  int i = blockIdx.x * 256 + threadIdx.x;
  if (i < 16384) {
    int n = i >> 7, k = i & 127;
    W2bt[i] = f2b(Wg2[k * 128 + n]);
  }
  int j = i - 16384;
  if (j >= 0 && j < 81920) {
    int n = j >> 7, k = j & 127;
    Wcomb[j] = f2b(n < 128 ? Wg1[k * 128 + n] : wih[(n - 128) * 128 + k]);
  }
  int q = i - (16384 + 81920);
  if (q >= 0 && q < 65536) whhb[q] = f2b(whh[q]);
  if (i < 512) bgate[i] = bih[i] + bhh[i];
}

// ---------------- batched MFMA GEMMs (M = 600000, K = 128) ----------------
#define LDT 40

// One A-staging, five output col-blocks of Wcomb (cb = 0..4, looped inside):
//   cb == 0 : z1[row] = ns[row/TT] * ( bf16(h[row]) @ Wg1 )       -> C (bf16)
//   cb >= 1 : xg[row][ (cb-1)*128 + col ] = f16( bf16(h[row]) @ w_ih^T )  (plane layout)
__global__ __launch_bounds__(256) void gemm_h_all(
    const float* __restrict__ A, const float* __restrict__ ns,
    const unsigned short* __restrict__ Wcomb, unsigned short* __restrict__ C,
    unsigned short* __restrict__ xg, int M) {
  __shared__ unsigned short As[4 * 128 * LDT];  // full K, 4 chunks of 32
  __shared__ unsigned short Bs[128 * LDT];
  const int tid = threadIdx.x;
  const int lane = tid & 63, wid = tid >> 6;
  const int quad = lane >> 4, l16 = lane & 15;
  const int row0 = blockIdx.x * 128;
  const int wm = (wid >> 1) * 64, wn = (wid & 1) * 64;

  // stage the full 128x128 A tile once (f32 -> bf16)
#pragma unroll
  for (int rds = 0; rds < 8; rds++) {
    int idx = rds * 256 + tid;        // 0..2047
    int m = idx >> 4;                 // row 0..127
    int k8 = (idx & 15) * 8;          // k offset 0..120
    int gr = row0 + m;
    if (gr >= M) gr = M - 1;
    const float4 va = *(const float4*)(A + (size_t)gr * 128 + k8);
    const float4 vb = *(const float4*)(A + (size_t)gr * 128 + k8 + 4);
    int chunk = k8 >> 5, c = k8 & 31;
    unsigned short* d = &As[(chunk * 128 + m) * LDT + c];
    d[0] = f2b(va.x); d[1] = f2b(va.y); d[2] = f2b(va.z); d[3] = f2b(va.w);
    d[4] = f2b(vb.x); d[5] = f2b(vb.y); d[6] = f2b(vb.z); d[7] = f2b(vb.w);
  }

  for (int cb = 0; cb < 5; cb++) {
    f32x4 acc[4][4] = {};
#pragma unroll
    for (int k0 = 0; k0 < 4; k0++) {
      __syncthreads();  // prev Bs reads done (also covers As staging on first iter)
      {
        int n = tid >> 1;
        int c = (tid & 1) * 16;
        const unsigned short* srcw = Wcomb + ((size_t)(cb * 128 + n)) * 128 + k0 * 32 + c;
        *(uint4*)(&Bs[n * LDT + c]) = *(const uint4*)srcw;
        *(uint4*)(&Bs[n * LDT + c + 8]) = *(const uint4*)(srcw + 8);
      }
      __syncthreads();
      bf16x8 af[4], bfr[4];
#pragma unroll
      for (int im = 0; im < 4; im++)
        af[im] = *(const bf16x8*)(&As[(k0 * 128 + wm + im * 16 + l16) * LDT + quad * 8]);
#pragma unroll
      for (int in = 0; in < 4; in++)
        bfr[in] = *(const bf16x8*)(&Bs[(wn + in * 16 + l16) * LDT + quad * 8]);
#pragma unroll
      for (int im = 0; im < 4; im++)
#pragma unroll
        for (int in = 0; in < 4; in++)
          acc[im][in] = __builtin_amdgcn_mfma_f32_16x16x32_bf16(af[im], bfr[in], acc[im][in], 0, 0, 0);
    }
    if (cb == 0) {
#pragma unroll
      for (int im = 0; im < 4; im++)
#pragma unroll
        for (int r = 0; r < 4; r++) {
          int row = row0 + wm + im * 16 + quad * 4 + r;
          if (row < M) {
            float s = ns[row / TT];
#pragma unroll
            for (int in = 0; in < 4; in++)
              C[(size_t)row * 128 + wn + in * 16 + l16] = f2b(acc[im][in][r] * s);
          }
        }
    } else {
      const int goff = (cb - 1) * 128;
#pragma unroll
      for (int im = 0; im < 4; im++)
#pragma unroll
        for (int r = 0; r < 4; r++) {
          int row = row0 + wm + im * 16 + quad * 4 + r;
          if (row < M)
#pragma unroll
            for (int in = 0; in < 4; in++)
              xg[(size_t)row * 512 + goff + wn + in * 16 + l16] = f2h(acc[im][in][r]);
        }
    }
  }
}

// z2 = y1s @ W2bt^T  (bf16 A)
__global__ __launch_bounds__(256) void gemm_bf16A(
    const unsigned short* __restrict__ A, const unsigned short* __restrict__ Bt,
    unsigned short* __restrict__ C, int M) {
  __shared__ unsigned short As[128 * LDT];
  __shared__ unsigned short Bs[128 * LDT];
  const int tid = threadIdx.x;
  const int lane = tid & 63, wid = tid >> 6;
  const int quad = lane >> 4, l16 = lane & 15;
  const int row0 = blockIdx.x * 128;
  const int wm = (wid >> 1) * 64, wn = (wid & 1) * 64;
  f32x4 acc[4][4] = {};
  for (int k0 = 0; k0 < 128; k0 += 32) {
#pragma unroll
    for (int rds = 0; rds < 2; rds++) {
      int idx = (rds * 256 + tid) * 8;
      int m = idx >> 5, c = idx & 31;
      int gr = row0 + m;
      if (gr >= M) gr = M - 1;
      *(uint4*)(&As[m * LDT + c]) = *(const uint4*)(A + (size_t)gr * 128 + k0 + c);
      *(uint4*)(&Bs[m * LDT + c]) = *(const uint4*)(Bt + m * 128 + k0 + c);
    }
    __syncthreads();
    bf16x8 af[4], bfr[4];
#pragma unroll
    for (int im = 0; im < 4; im++)
      af[im] = *(const bf16x8*)(&As[(wm + im * 16 + l16) * LDT + quad * 8]);
#pragma unroll
    for (int in = 0; in < 4; in++)
      bfr[in] = *(const bf16x8*)(&Bs[(wn + in * 16 + l16) * LDT + quad * 8]);
#pragma unroll
    for (int im = 0; im < 4; im++)
#pragma unroll
      for (int in = 0; in < 4; in++)
        acc[im][in] = __builtin_amdgcn_mfma_f32_16x16x32_bf16(af[im], bfr[in], acc[im][in], 0, 0, 0);
    __syncthreads();
  }
#pragma unroll
  for (int im = 0; im < 4; im++)
#pragma unroll
    for (int r = 0; r < 4; r++) {
      int row = row0 + wm + im * 16 + quad * 4 + r;
      if (row < M)
#pragma unroll
        for (int in = 0; in < 4; in++)
          C[(size_t)row * 128 + wn + in * 16 + l16] = f2b(acc[im][in][r]);
    }
}

// ---------------- batched SpMM ----------------

template <bool SCALE_OUT>
__global__ __launch_bounds__(256) void spmm_b(
    const unsigned short* __restrict__ z, const int* __restrict__ rowp,
    const int* __restrict__ colx, const float* __restrict__ ns,
    const float* __restrict__ nd, const float* __restrict__ bg,
    unsigned short* __restrict__ y) {
  int d = (blockIdx.x * 256 + threadIdx.x) >> 6;
  int lane = threadIdx.x & 63;
  if (d >= NN) return;
  int beg = rowp[d], end = rowp[d + 1];
  float acc[3][8] = {};
  int j = beg;
  int s = (j < end) ? colx[j] : 0;
  while (j < end) {
    int snext = (j + 1 < end) ? colx[j + 1] : 0;
    const unsigned short* base = z + (size_t)s * 1536 + lane * 8;
#pragma unroll
    for (int r = 0; r < 3; r++) {
      uint4 v = *(const uint4*)(base + r * 512);
      acc[r][0] += blo(v.x); acc[r][1] += bhi(v.x);
      acc[r][2] += blo(v.y); acc[r][3] += bhi(v.y);
      acc[r][4] += blo(v.z); acc[r][5] += bhi(v.z);
      acc[r][6] += blo(v.w); acc[r][7] += bhi(v.w);
    }
    s = snext;
    j++;
  }
  float scn = nd[d];
  float sco = SCALE_OUT ? ns[d] : 1.0f;
  float bgv[8];
#pragma unroll
  for (int k = 0; k < 8; k++) bgv[k] = bg[(lane * 8 + k) & 127];
  unsigned short* outp = y + (size_t)d * 1536 + lane * 8;
#pragma unroll
  for (int r = 0; r < 3; r++) {
    unsigned short o[8];
#pragma unroll
    for (int k = 0; k < 8; k++)
      o[k] = f2b(sco * geluf_(acc[r][k] * scn + bgv[k]));
    *(uint4*)(outp + r * 512) = *(const uint4*)o;
  }
}

// ---------------- batched column mean ----------------

__global__ void colmean_b(const unsigned short* __restrict__ x, float* __restrict__ out) {
  int t = blockIdx.x;
  int cc = threadIdx.x & 127;
  int half = threadIdx.x >> 7;
  float s = 0.f;
  for (int n = blockIdx.y * 2 + half; n < NN; n += 64)
    s += b2f(x[((size_t)n * TT + t) * 128 + cc]);
  __shared__ float sm[256];
  sm[threadIdx.x] = s;
  __syncthreads();
  if (threadIdx.x < 128)
    atomicAdd(&out[t * 128 + cc], (sm[threadIdx.x] + sm[threadIdx.x + 128]) * (1.0f / NN));
}

// ---------------- LSTM: h-recurrence only, w_hh resident in LDS ----------------
// block = 512 thr (8 waves), 64 rows. gates = xg (precomputed x@w_ih^T, f16,
// plane layout [row][g*128+col]) + Hp @ w_hh^T (MFMA from LDS-resident weights).
// Per t: 4 pure ds_read+MFMA k-steps, 2 barriers. t=0 skips MFMA (h_prev=0).
#define HPLD 136
#define WLD 136

__global__ __launch_bounds__(512, 2) void lstm_hh(
    const unsigned short* __restrict__ whhb, const unsigned short* __restrict__ xg,
    const float* __restrict__ bgate, float* __restrict__ ht_out, int M) {
  __shared__ unsigned short Ws[512 * WLD];  // 136 KB
  __shared__ unsigned short Hp[64 * HPLD];  // 17 KB
  const int tid = threadIdx.x;
  const int lane = tid & 63;
  const int w = tid >> 6;
  const int quad = lane >> 4, l16 = lane & 15;
  const int row0 = blockIdx.x * 64;
  const int colg = w * 16 + l16;

  // one-time weight staging: 512x128 bf16, 16B per thread-iter, coalesced
#pragma unroll
  for (int it = 0; it < 16; it++) {
    int idx = it * 512 + tid;
    int n = idx >> 4, c = (idx & 15) * 8;
    *(uint4*)(&Ws[n * WLD + c]) = *(const uint4*)(whhb + n * 128 + c);
  }

  float cs[4][4], hacc[4][4];
#pragma unroll
  for (int im = 0; im < 4; im++)
#pragma unroll
    for (int r = 0; r < 4; r++) { cs[im][r] = 0.f; hacc[im][r] = 0.f; }

  const float bi = bgate[colg], bff = bgate[128 + colg];
  const float bgg = bgate[256 + colg], bo = bgate[384 + colg];
  __syncthreads();

  for (int t = 0; t < TT; t++) {
    // prefetch this step's x-gates (4 plane loads per fragment) — hides under MFMA
    unsigned short xsv[4][4][4];  // [im][r][gate]
#pragma unroll
    for (int im = 0; im < 4; im++)
#pragma unroll
      for (int r = 0; r < 4; r++) {
        int gr = row0 + im * 16 + quad * 4 + r;
        int grc = gr < M ? gr : M - 1;
        const unsigned short* xp = xg + ((size_t)grc * TT + t) * 512 + colg;
#pragma unroll
        for (int g = 0; g < 4; g++) xsv[im][r][g] = xp[g * 128];
      }

    f32x4 acc[4][4] = {};  // [im][gate]
    if (t) {
#pragma unroll
      for (int k0 = 0; k0 < 128; k0 += 32) {
        bf16x8 af[4];
#pragma unroll
        for (int im = 0; im < 4; im++)
          af[im] = *(const bf16x8*)(&Hp[(im * 16 + l16) * HPLD + k0 + quad * 8]);
#pragma unroll
        for (int g = 0; g < 4; g++) {
          bf16x8 bf = *(const bf16x8*)(&Ws[(g * 128 + colg) * WLD + k0 + quad * 8]);
#pragma unroll
          for (int im = 0; im < 4; im++)
            acc[im][g] = __builtin_amdgcn_mfma_f32_16x16x32_bf16(af[im], bf, acc[im][g], 0, 0, 0);
        }
      }
      __syncthreads();  // all waves done reading Hp for this t
    }

    // fused pointwise; h stays in LDS, c stays in registers
#pragma unroll
    for (int im = 0; im < 4; im++)
#pragma unroll
      for (int r = 0; r < 4; r++) {
        float iv = sigmoidf_(acc[im][0][r] + h2f(xsv[im][r][0]) + bi);
        float fv = sigmoidf_(acc[im][1][r] + h2f(xsv[im][r][1]) + bff);
        float gv = tanhf(acc[im][2][r] + h2f(xsv[im][r][2]) + bgg);
        float ov = sigmoidf_(acc[im][3][r] + h2f(xsv[im][r][3]) + bo);
        float cn = fv * cs[im][r] + iv * gv;
        cs[im][r] = cn;
        float ho = ov * tanhf(cn);
        hacc[im][r] += ho;
        Hp[(im * 16 + quad * 4 + r) * HPLD + colg] = f2b(ho);
      }
    __syncthreads();
  }
#pragma unroll
  for (int im = 0; im < 4; im++)
#pragma unroll
    for (int r = 0; r < 4; r++) {
      int gr = row0 + im * 16 + quad * 4 + r;
      if (gr < M) ht_out[(size_t)gr * 128 + colg] = hacc[im][r] * (1.0f / TT);
    }
}

// ---------------- host ----------------

extern "C" void kernel_launch(void* const* d_in, const int* in_sizes, int n_in,
                              void* d_out, int out_size, void* d_ws, size_t ws_size,
                              hipStream_t stream) {
  const float* h   = (const float*)d_in[0];
  const int*   src = (const int*)d_in[1];
  const int*   dst = (const int*)d_in[2];
  const float* Wg1 = (const float*)d_in[3];
  const float* bg1 = (const float*)d_in[4];
  const float* Wg2 = (const float*)d_in[5];
  const float* bg2 = (const float*)d_in[6];
  const float* wih = (const float*)d_in[7];
  const float* whh = (const float*)d_in[8];
  const float* bih = (const float*)d_in[9];
  const float* bhh = (const float*)d_in[10];

  float* out = (float*)d_out;
  float* hs_out = out;            // 12*128
  float* ht_out = out + TT * DIM; // N*128

  char* p = (char*)d_ws;
  auto alloc = [&](size_t bytes) -> void* {
    void* r = (void*)p;
    p += (bytes + 255) & ~(size_t)255;
    return r;
  };
  const size_t MB = (size_t)NN * TT * DIM;  // 76.8M elements
  unsigned short* bufA = (unsigned short*)alloc(MB * 2);            // z1 -> z2
  unsigned short* bufB = (unsigned short*)alloc(MB * 2);            // y1s -> y2
  unsigned short* xgb  = (unsigned short*)alloc((size_t)NN * TT * 512 * 2);  // x-gates f16
  unsigned short* W2bt = (unsigned short*)alloc(16384 * 2);
  unsigned short* Wcomb= (unsigned short*)alloc(81920 * 2);
  unsigned short* whhb = (unsigned short*)alloc(65536 * 2);
  float* bgate = (float*)alloc(512 * 4);
  float* ns    = (float*)alloc(NN * 4);
  float* nd    = (float*)alloc(NN * 4);
  int* degs    = (int*)alloc(NN * 4);
  int* degd    = (int*)alloc(NN * 4);
  int* rowp    = (int*)alloc((NN + 1) * 4);
  int* colx    = (int*)alloc(EE * 4);

  hipMemsetAsync(degs, 0, NN * 4, stream);
  hipMemsetAsync(degd, 0, NN * 4, stream);
  hipMemsetAsync(hs_out, 0, TT * DIM * 4, stream);

  deg_kernel<<<(EE + 255) / 256, 256, 0, stream>>>(src, dst, degs, degd);
  norm_kernel<<<(NN + 255) / 256, 256, 0, stream>>>(degs, degd, ns, nd);
  scan_kernel<<<1, 1024, 0, stream>>>(degd, rowp, NN);
  hipMemsetAsync(degs, 0, NN * 4, stream);  // reuse as fill counters
  csr_kernel<<<(EE + 255) / 256, 256, 0, stream>>>(src, dst, rowp, degs, colx);
  prep_w<<<(16384 + 81920 + 65536 + 255) / 256, 256, 0, stream>>>(
      Wg1, Wg2, wih, whh, bih, bhh, W2bt, Wcomb, whhb, bgate);

  const int M = NN * TT;                  // 600000 batched rows
  const int gblocks = (M + 127) / 128;    // 4688
  const int sblocks = (NN + 3) / 4;       // wave per dst row

  // GCN gemm1 fused with x-gate precompute (cb looped inside; h read once)
  gemm_h_all<<<gblocks, 256, 0, stream>>>(h, ns, Wcomb, bufA, xgb, M);
  spmm_b<true><<<sblocks, 256, 0, stream>>>(bufA, rowp, colx, ns, nd, bg1, bufB);
  gemm_bf16A<<<gblocks, 256, 0, stream>>>(bufB, W2bt, bufA, M);
  spmm_b<false><<<sblocks, 256, 0, stream>>>(bufA, rowp, colx, ns, nd, bg2, bufB);
  colmean_b<<<dim3(TT, 32), 256, 0, stream>>>(bufB, hs_out);

  // LSTM: h-recurrence only, weights LDS-resident
  lstm_hh<<<(NN + 63) / 64, 512, 0, stream>>>(whhb, xgb, bgate, ht_out, NN);
}

// Round 3
// 2313.284 us; speedup vs baseline: 1.2454x; 1.0558x over previous
//
#include <hip/hip_runtime.h>
#include <math.h>

#define NN 50000
#define TT 12
#define EE 800000
#define DIM 128

typedef short bf16x8 __attribute__((ext_vector_type(8)));
typedef float f32x4 __attribute__((ext_vector_type(4)));

__device__ __forceinline__ float sigmoidf_(float x) { return 1.0f / (1.0f + expf(-x)); }
__device__ __forceinline__ float geluf_(float x) {
  return 0.5f * x * (1.0f + erff(x * 0.70710678118654752440f));
}
// fast branch-free transcendentals (1-2 ulp f32; saturate correctly via inf/0)
#define LOG2E 1.44269504088896340736f
__device__ __forceinline__ float fsigmoid(float x) {
  return __builtin_amdgcn_rcpf(1.0f + __builtin_amdgcn_exp2f(-LOG2E * x));
}
__device__ __forceinline__ float ftanh(float x) {
  return 1.0f - 2.0f * __builtin_amdgcn_rcpf(1.0f + __builtin_amdgcn_exp2f((2.0f * LOG2E) * x));
}
__device__ __forceinline__ unsigned short f2b(float f) {
  union { float f; unsigned u; } v;
  v.f = f;
  unsigned r = (v.u + 0x7fffu + ((v.u >> 16) & 1u)) >> 16;
  return (unsigned short)r;
}
__device__ __forceinline__ float blo(unsigned u) {
  union { unsigned x; float f; } v; v.x = u << 16; return v.f;
}
__device__ __forceinline__ float bhi(unsigned u) {
  union { unsigned x; float f; } v; v.x = u & 0xffff0000u; return v.f;
}
__device__ __forceinline__ float b2f(unsigned short b) {
  union { unsigned u; float f; } v; v.u = ((unsigned)b) << 16; return v.f;
}
__device__ __forceinline__ unsigned short f2h(float f) {
  union { _Float16 h; unsigned short s; } v; v.h = (_Float16)f; return v.s;
}
__device__ __forceinline__ float h2f(unsigned short u) {
  union { unsigned short s; _Float16 h; } v; v.s = u; return (float)v.h;
}

// ---------------- graph preprocessing ----------------

__global__ void deg_kernel(const int* __restrict__ src, const int* __restrict__ dst,
                           int* __restrict__ ds, int* __restrict__ dd) {
  int e = blockIdx.x * 256 + threadIdx.x;
  if (e < EE) {
    atomicAdd(&ds[src[e]], 1);
    atomicAdd(&dd[dst[e]], 1);
  }
}

__global__ void norm_kernel(const int* __restrict__ ds, const int* __restrict__ dd,
                            float* __restrict__ ns, float* __restrict__ nd) {
  int i = blockIdx.x * 256 + threadIdx.x;
  if (i < NN) {
    ns[i] = rsqrtf((float)(ds[i] > 1 ? ds[i] : 1));
    nd[i] = rsqrtf((float)(dd[i] > 1 ? dd[i] : 1));
  }
}

__global__ void scan_kernel(const int* __restrict__ cnt, int* __restrict__ row_ptr, int n) {
  __shared__ int sm[1024];
  __shared__ int carry;
  int tid = threadIdx.x;
  if (tid == 0) carry = 0;
  __syncthreads();
  for (int base = 0; base < n; base += 1024) {
    int v = (base + tid < n) ? cnt[base + tid] : 0;
    sm[tid] = v;
    __syncthreads();
    for (int off = 1; off < 1024; off <<= 1) {
      int t = (tid >= off) ? sm[tid - off] : 0;
      __syncthreads();
      sm[tid] += t;
      __syncthreads();
    }
    int incl = sm[tid];
    if (base + tid < n) row_ptr[base + tid] = carry + incl - v;
    int tot = sm[1023];
    __syncthreads();
    if (tid == 0) carry += tot;
    __syncthreads();
  }
  if (tid == 0) row_ptr[n] = carry;
}

__global__ void csr_kernel(const int* __restrict__ src, const int* __restrict__ dst,
                           const int* __restrict__ row_ptr, int* __restrict__ fill,
                           int* __restrict__ col) {
  int e = blockIdx.x * 256 + threadIdx.x;
  if (e < EE) {
    int d = dst[e];
    int pos = row_ptr[d] + atomicAdd(&fill[d], 1);
    col[pos] = src[e];
  }
}

// ---------------- weight prep ----------------
// W2bt: [128][128] n-major = Wg2^T (bf16)
// Wcomb: [640][128] n-major: rows 0..127 = Wg1^T, rows 128..639 = w_ih (bf16)
// whhb:  [512][128] n-major = w_hh (bf16)
// bgate: b_ih + b_hh

__global__ void prep_w(const float* __restrict__ Wg1, const float* __restrict__ Wg2,
                       const float* __restrict__ wih, const float* __restrict__ whh,
                       const float* __restrict__ bih, const float* __restrict__ bhh,
                       unsigned short* __restrict__ W2bt, unsigned short* __restrict__ Wcomb,
                       unsigned short* __restrict__ whhb, float* __restrict__ bgate) {
  int i = blockIdx.x * 256 + threadIdx.x;
  if (i < 16384) {
    int n = i >> 7, k = i & 127;
    W2bt[i] = f2b(Wg2[k * 128 + n]);
  }
  int j = i - 16384;
  if (j >= 0 && j < 81920) {
    int n = j >> 7, k = j & 127;
    Wcomb[j] = f2b(n < 128 ? Wg1[k * 128 + n] : wih[(n - 128) * 128 + k]);
  }
  int q = i - (16384 + 81920);
  if (q >= 0 && q < 65536) whhb[q] = f2b(whh[q]);
  if (i < 512) bgate[i] = bih[i] + bhh[i];
}

// ---------------- batched MFMA GEMMs (M = 600000, K = 128) ----------------
#define LDT 40

// One A-staging, five output col-blocks of Wcomb (cb = 0..4, looped inside):
//   cb == 0 : z1[row] = ns[row/TT] * ( bf16(h[row]) @ Wg1 )       -> C (bf16)
//   cb >= 1 : xg[row][ (cb-1)*128 + col ] = f16( bf16(h[row]) @ w_ih^T )  (plane layout)
__global__ __launch_bounds__(256) void gemm_h_all(
    const float* __restrict__ A, const float* __restrict__ ns,
    const unsigned short* __restrict__ Wcomb, unsigned short* __restrict__ C,
    unsigned short* __restrict__ xg, int M) {
  __shared__ unsigned short As[4 * 128 * LDT];  // full K, 4 chunks of 32
  __shared__ unsigned short Bs[128 * LDT];
  const int tid = threadIdx.x;
  const int lane = tid & 63, wid = tid >> 6;
  const int quad = lane >> 4, l16 = lane & 15;
  const int row0 = blockIdx.x * 128;
  const int wm = (wid >> 1) * 64, wn = (wid & 1) * 64;

  // stage the full 128x128 A tile once (f32 -> bf16)
#pragma unroll
  for (int rds = 0; rds < 8; rds++) {
    int idx = rds * 256 + tid;        // 0..2047
    int m = idx >> 4;                 // row 0..127
    int k8 = (idx & 15) * 8;          // k offset 0..120
    int gr = row0 + m;
    if (gr >= M) gr = M - 1;
    const float4 va = *(const float4*)(A + (size_t)gr * 128 + k8);
    const float4 vb = *(const float4*)(A + (size_t)gr * 128 + k8 + 4);
    int chunk = k8 >> 5, c = k8 & 31;
    unsigned short* d = &As[(chunk * 128 + m) * LDT + c];
    d[0] = f2b(va.x); d[1] = f2b(va.y); d[2] = f2b(va.z); d[3] = f2b(va.w);
    d[4] = f2b(vb.x); d[5] = f2b(vb.y); d[6] = f2b(vb.z); d[7] = f2b(vb.w);
  }

  for (int cb = 0; cb < 5; cb++) {
    f32x4 acc[4][4] = {};
#pragma unroll
    for (int k0 = 0; k0 < 4; k0++) {
      __syncthreads();  // prev Bs reads done (also covers As staging on first iter)
      {
        int n = tid >> 1;
        int c = (tid & 1) * 16;
        const unsigned short* srcw = Wcomb + ((size_t)(cb * 128 + n)) * 128 + k0 * 32 + c;
        *(uint4*)(&Bs[n * LDT + c]) = *(const uint4*)srcw;
        *(uint4*)(&Bs[n * LDT + c + 8]) = *(const uint4*)(srcw + 8);
      }
      __syncthreads();
      bf16x8 af[4], bfr[4];
#pragma unroll
      for (int im = 0; im < 4; im++)
        af[im] = *(const bf16x8*)(&As[(k0 * 128 + wm + im * 16 + l16) * LDT + quad * 8]);
#pragma unroll
      for (int in = 0; in < 4; in++)
        bfr[in] = *(const bf16x8*)(&Bs[(wn + in * 16 + l16) * LDT + quad * 8]);
#pragma unroll
      for (int im = 0; im < 4; im++)
#pragma unroll
        for (int in = 0; in < 4; in++)
          acc[im][in] = __builtin_amdgcn_mfma_f32_16x16x32_bf16(af[im], bfr[in], acc[im][in], 0, 0, 0);
    }
    if (cb == 0) {
#pragma unroll
      for (int im = 0; im < 4; im++)
#pragma unroll
        for (int r = 0; r < 4; r++) {
          int row = row0 + wm + im * 16 + quad * 4 + r;
          if (row < M) {
            float s = ns[row / TT];
#pragma unroll
            for (int in = 0; in < 4; in++)
              C[(size_t)row * 128 + wn + in * 16 + l16] = f2b(acc[im][in][r] * s);
          }
        }
    } else {
      const int goff = (cb - 1) * 128;
#pragma unroll
      for (int im = 0; im < 4; im++)
#pragma unroll
        for (int r = 0; r < 4; r++) {
          int row = row0 + wm + im * 16 + quad * 4 + r;
          if (row < M)
#pragma unroll
            for (int in = 0; in < 4; in++)
              xg[(size_t)row * 512 + goff + wn + in * 16 + l16] = f2h(acc[im][in][r]);
        }
    }
  }
}

// z2 = y1s @ W2bt^T  (bf16 A)
__global__ __launch_bounds__(256) void gemm_bf16A(
    const unsigned short* __restrict__ A, const unsigned short* __restrict__ Bt,
    unsigned short* __restrict__ C, int M) {
  __shared__ unsigned short As[128 * LDT];
  __shared__ unsigned short Bs[128 * LDT];
  const int tid = threadIdx.x;
  const int lane = tid & 63, wid = tid >> 6;
  const int quad = lane >> 4, l16 = lane & 15;
  const int row0 = blockIdx.x * 128;
  const int wm = (wid >> 1) * 64, wn = (wid & 1) * 64;
  f32x4 acc[4][4] = {};
  for (int k0 = 0; k0 < 128; k0 += 32) {
#pragma unroll
    for (int rds = 0; rds < 2; rds++) {
      int idx = (rds * 256 + tid) * 8;
      int m = idx >> 5, c = idx & 31;
      int gr = row0 + m;
      if (gr >= M) gr = M - 1;
      *(uint4*)(&As[m * LDT + c]) = *(const uint4*)(A + (size_t)gr * 128 + k0 + c);
      *(uint4*)(&Bs[m * LDT + c]) = *(const uint4*)(Bt + m * 128 + k0 + c);
    }
    __syncthreads();
    bf16x8 af[4], bfr[4];
#pragma unroll
    for (int im = 0; im < 4; im++)
      af[im] = *(const bf16x8*)(&As[(wm + im * 16 + l16) * LDT + quad * 8]);
#pragma unroll
    for (int in = 0; in < 4; in++)
      bfr[in] = *(const bf16x8*)(&Bs[(wn + in * 16 + l16) * LDT + quad * 8]);
#pragma unroll
    for (int im = 0; im < 4; im++)
#pragma unroll
      for (int in = 0; in < 4; in++)
        acc[im][in] = __builtin_amdgcn_mfma_f32_16x16x32_bf16(af[im], bfr[in], acc[im][in], 0, 0, 0);
    __syncthreads();
  }
#pragma unroll
  for (int im = 0; im < 4; im++)
#pragma unroll
    for (int r = 0; r < 4; r++) {
      int row = row0 + wm + im * 16 + quad * 4 + r;
      if (row < M)
#pragma unroll
        for (int in = 0; in < 4; in++)
          C[(size_t)row * 128 + wn + in * 16 + l16] = f2b(acc[im][in][r]);
    }
}

// ---------------- batched SpMM ----------------

template <bool SCALE_OUT>
__global__ __launch_bounds__(256) void spmm_b(
    const unsigned short* __restrict__ z, const int* __restrict__ rowp,
    const int* __restrict__ colx, const float* __restrict__ ns,
    const float* __restrict__ nd, const float* __restrict__ bg,
    unsigned short* __restrict__ y) {
  int d = (blockIdx.x * 256 + threadIdx.x) >> 6;
  int lane = threadIdx.x & 63;
  if (d >= NN) return;
  int beg = rowp[d], end = rowp[d + 1];
  float acc[3][8] = {};
  int j = beg;
  int s = (j < end) ? colx[j] : 0;
  while (j < end) {
    int snext = (j + 1 < end) ? colx[j + 1] : 0;
    const unsigned short* base = z + (size_t)s * 1536 + lane * 8;
#pragma unroll
    for (int r = 0; r < 3; r++) {
      uint4 v = *(const uint4*)(base + r * 512);
      acc[r][0] += blo(v.x); acc[r][1] += bhi(v.x);
      acc[r][2] += blo(v.y); acc[r][3] += bhi(v.y);
      acc[r][4] += blo(v.z); acc[r][5] += bhi(v.z);
      acc[r][6] += blo(v.w); acc[r][7] += bhi(v.w);
    }
    s = snext;
    j++;
  }
  float scn = nd[d];
  float sco = SCALE_OUT ? ns[d] : 1.0f;
  float bgv[8];
#pragma unroll
  for (int k = 0; k < 8; k++) bgv[k] = bg[(lane * 8 + k) & 127];
  unsigned short* outp = y + (size_t)d * 1536 + lane * 8;
#pragma unroll
  for (int r = 0; r < 3; r++) {
    unsigned short o[8];
#pragma unroll
    for (int k = 0; k < 8; k++)
      o[k] = f2b(sco * geluf_(acc[r][k] * scn + bgv[k]));
    *(uint4*)(outp + r * 512) = *(const uint4*)o;
  }
}

// ---------------- batched column mean ----------------

__global__ void colmean_b(const unsigned short* __restrict__ x, float* __restrict__ out) {
  int t = blockIdx.x;
  int cc = threadIdx.x & 127;
  int half = threadIdx.x >> 7;
  float s = 0.f;
  for (int n = blockIdx.y * 2 + half; n < NN; n += 64)
    s += b2f(x[((size_t)n * TT + t) * 128 + cc]);
  __shared__ float sm[256];
  sm[threadIdx.x] = s;
  __syncthreads();
  if (threadIdx.x < 128)
    atomicAdd(&out[t * 128 + cc], (sm[threadIdx.x] + sm[threadIdx.x + 128]) * (1.0f / NN));
}

// ---------------- LSTM: h-recurrence only, w_hh resident in REGISTERS --------
// block = 512 thr (8 waves), 64 rows. gates = xg (precomputed x@w_ih^T, f16,
// plane layout [row][g*128+col]) + Hp @ w_hh^T. Each thread's 16 B-fragments
// of w_hh are t-invariant -> loaded once into 64 VGPRs. LDS holds only Hp.
// Per t: 4 pure ds_read+MFMA k-steps, 2 barriers. t=0 skips MFMA (h_prev=0).
#define HPLD 136

__global__ __launch_bounds__(512, 2) void lstm_hh(
    const unsigned short* __restrict__ whhb, const unsigned short* __restrict__ xg,
    const float* __restrict__ bgate, float* __restrict__ ht_out, int M) {
  __shared__ unsigned short Hp[64 * HPLD];  // 17 KB
  const int tid = threadIdx.x;
  const int lane = tid & 63;
  const int w = tid >> 6;
  const int quad = lane >> 4, l16 = lane & 15;
  const int row0 = blockIdx.x * 64;
  const int colg = w * 16 + l16;

  // t-invariant B-fragments: bw[g][k0] = w_hh row (g*128+colg), k = k0*32 + quad*8
  bf16x8 bw[4][4];
#pragma unroll
  for (int g = 0; g < 4; g++)
#pragma unroll
    for (int k0 = 0; k0 < 4; k0++)
      bw[g][k0] = *(const bf16x8*)(whhb + ((size_t)(g * 128 + colg)) * 128 + k0 * 32 + quad * 8);

  float cs[4][4], hacc[4][4];
#pragma unroll
  for (int im = 0; im < 4; im++)
#pragma unroll
    for (int r = 0; r < 4; r++) { cs[im][r] = 0.f; hacc[im][r] = 0.f; }

  const float bi = bgate[colg], bff = bgate[128 + colg];
  const float bgg = bgate[256 + colg], bo = bgate[384 + colg];

  for (int t = 0; t < TT; t++) {
    f32x4 acc[4][4] = {};  // [im][gate]
    if (t) {
#pragma unroll
      for (int k0 = 0; k0 < 4; k0++) {
        bf16x8 af[4];
#pragma unroll
        for (int im = 0; im < 4; im++)
          af[im] = *(const bf16x8*)(&Hp[(im * 16 + l16) * HPLD + k0 * 32 + quad * 8]);
#pragma unroll
        for (int g = 0; g < 4; g++)
#pragma unroll
          for (int im = 0; im < 4; im++)
            acc[im][g] = __builtin_amdgcn_mfma_f32_16x16x32_bf16(af[im], bw[g][k0], acc[im][g], 0, 0, 0);
      }
    }

    // x-gate loads issued here: overlap the Hp barrier wait
    unsigned short xsv[4][4][4];  // [im][r][gate]
#pragma unroll
    for (int im = 0; im < 4; im++)
#pragma unroll
      for (int r = 0; r < 4; r++) {
        int gr = row0 + im * 16 + quad * 4 + r;
        int grc = gr < M ? gr : M - 1;
        const unsigned short* xp = xg + ((size_t)grc * TT + t) * 512 + colg;
#pragma unroll
        for (int g = 0; g < 4; g++) xsv[im][r][g] = xp[g * 128];
      }

    if (t) __syncthreads();  // all waves done reading Hp for this t

    // fused pointwise; h stays in LDS, c stays in registers
#pragma unroll
    for (int im = 0; im < 4; im++)
#pragma unroll
      for (int r = 0; r < 4; r++) {
        float iv = fsigmoid(acc[im][0][r] + h2f(xsv[im][r][0]) + bi);
        float fv = fsigmoid(acc[im][1][r] + h2f(xsv[im][r][1]) + bff);
        float gv = ftanh(acc[im][2][r] + h2f(xsv[im][r][2]) + bgg);
        float ov = fsigmoid(acc[im][3][r] + h2f(xsv[im][r][3]) + bo);
        float cn = fv * cs[im][r] + iv * gv;
        cs[im][r] = cn;
        float ho = ov * ftanh(cn);
        hacc[im][r] += ho;
        Hp[(im * 16 + quad * 4 + r) * HPLD + colg] = f2b(ho);
      }
    __syncthreads();
  }
#pragma unroll
  for (int im = 0; im < 4; im++)
#pragma unroll
    for (int r = 0; r < 4; r++) {
      int gr = row0 + im * 16 + quad * 4 + r;
      if (gr < M) ht_out[(size_t)gr * 128 + colg] = hacc[im][r] * (1.0f / TT);
    }
}

// ---------------- host ----------------

extern "C" void kernel_launch(void* const* d_in, const int* in_sizes, int n_in,
                              void* d_out, int out_size, void* d_ws, size_t ws_size,
                              hipStream_t stream) {
  const float* h   = (const float*)d_in[0];
  const int*   src = (const int*)d_in[1];
  const int*   dst = (const int*)d_in[2];
  const float* Wg1 = (const float*)d_in[3];
  const float* bg1 = (const float*)d_in[4];
  const float* Wg2 = (const float*)d_in[5];
  const float* bg2 = (const float*)d_in[6];
  const float* wih = (const float*)d_in[7];
  const float* whh = (const float*)d_in[8];
  const float* bih = (const float*)d_in[9];
  const float* bhh = (const float*)d_in[10];

  float* out = (float*)d_out;
  float* hs_out = out;            // 12*128
  float* ht_out = out + TT * DIM; // N*128

  char* p = (char*)d_ws;
  auto alloc = [&](size_t bytes) -> void* {
    void* r = (void*)p;
    p += (bytes + 255) & ~(size_t)255;
    return r;
  };
  const size_t MB = (size_t)NN * TT * DIM;  // 76.8M elements
  unsigned short* bufA = (unsigned short*)alloc(MB * 2);            // z1 -> z2
  unsigned short* bufB = (unsigned short*)alloc(MB * 2);            // y1s -> y2
  unsigned short* xgb  = (unsigned short*)alloc((size_t)NN * TT * 512 * 2);  // x-gates f16
  unsigned short* W2bt = (unsigned short*)alloc(16384 * 2);
  unsigned short* Wcomb= (unsigned short*)alloc(81920 * 2);
  unsigned short* whhb = (unsigned short*)alloc(65536 * 2);
  float* bgate = (float*)alloc(512 * 4);
  float* ns    = (float*)alloc(NN * 4);
  float* nd    = (float*)alloc(NN * 4);
  int* degs    = (int*)alloc(NN * 4);
  int* degd    = (int*)alloc(NN * 4);
  int* rowp    = (int*)alloc((NN + 1) * 4);
  int* colx    = (int*)alloc(EE * 4);

  hipMemsetAsync(degs, 0, NN * 4, stream);
  hipMemsetAsync(degd, 0, NN * 4, stream);
  hipMemsetAsync(hs_out, 0, TT * DIM * 4, stream);

  deg_kernel<<<(EE + 255) / 256, 256, 0, stream>>>(src, dst, degs, degd);
  norm_kernel<<<(NN + 255) / 256, 256, 0, stream>>>(degs, degd, ns, nd);
  scan_kernel<<<1, 1024, 0, stream>>>(degd, rowp, NN);
  hipMemsetAsync(degs, 0, NN * 4, stream);  // reuse as fill counters
  csr_kernel<<<(EE + 255) / 256, 256, 0, stream>>>(src, dst, rowp, degs, colx);
  prep_w<<<(16384 + 81920 + 65536 + 255) / 256, 256, 0, stream>>>(
      Wg1, Wg2, wih, whh, bih, bhh, W2bt, Wcomb, whhb, bgate);

  const int M = NN * TT;                  // 600000 batched rows
  const int gblocks = (M + 127) / 128;    // 4688
  const int sblocks = (NN + 3) / 4;       // wave per dst row

  // GCN gemm1 fused with x-gate precompute (cb looped inside; h read once)
  gemm_h_all<<<gblocks, 256, 0, stream>>>(h, ns, Wcomb, bufA, xgb, M);
  spmm_b<true><<<sblocks, 256, 0, stream>>>(bufA, rowp, colx, ns, nd, bg1, bufB);
  gemm_bf16A<<<gblocks, 256, 0, stream>>>(bufB, W2bt, bufA, M);
  spmm_b<false><<<sblocks, 256, 0, stream>>>(bufA, rowp, colx, ns, nd, bg2, bufB);
  colmean_b<<<dim3(TT, 32), 256, 0, stream>>>(bufB, hs_out);

  // LSTM: h-recurrence only, weights in registers
  lstm_hh<<<(NN + 63) / 64, 512, 0, stream>>>(whhb, xgb, bgate, ht_out, NN);
}